// Round 1
// baseline (199.842 us; speedup 1.0000x reference)
//
#include <hip/hip_runtime.h>
#include <math.h>

#define NWL   112
#define NCOLS 111          // END - START = 111 usable columns
#define NATM  84
#define THREADS 256
#define WAVES_PER_BLOCK 4
#define MAIN_BLOCKS 2048

__device__ __forceinline__ float wave_reduce_sum(float v) {
#pragma unroll
    for (int off = 32; off >= 1; off >>= 1)
        v += __shfl_xor(v, off, 64);
    return v;
}

__global__ __launch_bounds__(THREADS) void wfa_main(
    const float* __restrict__ stokes,   // (B, 4, 112)
    const float* __restrict__ pred,     // (B, 84)
    const float* __restrict__ targ,     // (B, 84)
    const float* __restrict__ wl,       // (112)
    float* __restrict__ ws,             // partials: [nblk] base, [nblk] wfa, [nblk] cnt
    int nrows, int nblocks)
{
    __shared__ float s_inv_dwl[NWL];
    __shared__ float s_I[WAVES_PER_BLOCK][NWL];
    __shared__ float s_red[WAVES_PER_BLOCK][3];

    const int tid  = threadIdx.x;
    const int lane = tid & 63;
    const int wid  = tid >> 6;

    // dwl from the ACTUAL float32 wavelengths (per-j variation ~1% due to
    // float32 cancellation in wl[j+1]-wl[j-1] -- must not assume uniform).
    if (tid < NCOLS) {
        int j = tid;
        float d;
        if (j == 0)            d = wl[1] - wl[0];
        else if (j == NCOLS-1) d = wl[NCOLS-1] - wl[NCOLS-2];
        else                   d = 0.5f * (wl[j+1] - wl[j-1]);
        s_inv_dwl[j] = 1.0f / d;
    }
    __syncthreads();

    const int gwave  = blockIdx.x * WAVES_PER_BLOCK + wid;
    const int nwaves = nblocks * WAVES_PER_BLOCK;

    const int  c1   = lane + 64;
    const bool has1 = (c1 < NCOLS);   // lanes 0..46 hold a second column

    // -p0 / (WFA_C * LAMBDA0^2 * G_FACTOR), constant computed in double then cast
    const float WFA_DEN = (float)(4.6686e-13 * 6301.5 * 6301.5 * 1.5);

    float base_acc = 0.f;
    float wfa_acc  = 0.f;   // lane 0 only
    float cnt_acc  = 0.f;   // lane 0 only

    float* sI = s_I[wid];

    for (int r = gwave; r < nrows; r += nwaves) {
        const float* rowI = stokes + (size_t)r * (4 * NWL);
        const float* rowV = rowI + 3 * NWL;

        float i0 = rowI[lane];
        float i1 = has1 ? rowI[c1] : 0.f;
        float v0 = rowV[lane];
        float v1 = has1 ? rowV[c1] : 0.f;

        // base-loss partial: 84 floats = 21 float4 (row stride 336 B, 16B-aligned)
        float bpart = 0.f;
        if (lane < 21) {
            const float4 p4 = ((const float4*)(pred + (size_t)r * NATM))[lane];
            const float4 t4 = ((const float4*)(targ + (size_t)r * NATM))[lane];
            bpart = fabsf(p4.x - t4.x) + fabsf(p4.y - t4.y)
                  + fabsf(p4.z - t4.z) + fabsf(p4.w - t4.w);
        }
        base_acc += bpart;

        // stage I in this wave's LDS slice (same-wave ordering: no barrier)
        sI[lane] = i0;
        if (has1) sI[c1] = i1;

        // dI = np.gradient(I) / dwl
        float dI0;
        {
            const int j = lane;                       // 0..63, never the right edge
            float g = (j == 0) ? (sI[1] - sI[0])
                               : 0.5f * (sI[j + 1] - sI[j - 1]);
            dI0 = g * s_inv_dwl[j];
        }
        float dI1 = 0.f;
        if (has1) {
            const int j = c1;                         // 64..110
            float g = (j == NCOLS - 1) ? (sI[j] - sI[j - 1])
                                       : 0.5f * (sI[j + 1] - sI[j - 1]);
            dI1 = g * s_inv_dwl[j];
        }

        const float sd  = wave_reduce_sum(dI0 + dI1);
        const float sdd = wave_reduce_sum(dI0 * dI0 + dI1 * dI1);
        const float sdv = wave_reduce_sum(dI0 * v0 + dI1 * v1);
        const float sv  = wave_reduce_sum(v0 + v1);

        if (lane == 0) {
            const float n  = (float)NCOLS;
            const float p0 = (n * sdv - sd * sv) / (n * sdd - sd * sd);
            const float wb = -p0 / WFA_DEN;
            const float ab = fabsf(wb);
            if (ab < 100.0f) {
                const float* a = pred + (size_t)r * NATM;
                const float pb = (a[3] + a[7] + a[11]) / 3.0f;
                wfa_acc += fabsf(log10f(fabsf(pb) + 1e-10f) - log10f(ab + 1e-10f));
                cnt_acc += 1.0f;
            }
        }
    }

    base_acc = wave_reduce_sum(base_acc);
    if (lane == 0) {
        s_red[wid][0] = base_acc;
        s_red[wid][1] = wfa_acc;
        s_red[wid][2] = cnt_acc;
    }
    __syncthreads();
    if (tid == 0) {
        float b = 0.f, w = 0.f, c = 0.f;
#pragma unroll
        for (int k = 0; k < WAVES_PER_BLOCK; ++k) {
            b += s_red[k][0]; w += s_red[k][1]; c += s_red[k][2];
        }
        ws[blockIdx.x]               = b;
        ws[nblocks + blockIdx.x]     = w;
        ws[2 * nblocks + blockIdx.x] = c;
    }
}

__global__ __launch_bounds__(256) void wfa_final(
    const float* __restrict__ ws, float* __restrict__ out,
    int nblocks, int nrows)
{
    const int tid = threadIdx.x;
    float b = 0.f, w = 0.f, c = 0.f;
    for (int i = tid; i < nblocks; i += 256) {
        b += ws[i];
        w += ws[nblocks + i];
        c += ws[2 * nblocks + i];
    }
    b = wave_reduce_sum(b);
    w = wave_reduce_sum(w);
    c = wave_reduce_sum(c);

    __shared__ float sb[4], sw[4], sc[4];
    const int lane = tid & 63, wid = tid >> 6;
    if (lane == 0) { sb[wid] = b; sw[wid] = w; sc[wid] = c; }
    __syncthreads();
    if (tid == 0) {
        const float B_ = sb[0] + sb[1] + sb[2] + sb[3];
        const float W_ = sw[0] + sw[1] + sw[2] + sw[3];
        const float C_ = sc[0] + sc[1] + sc[2] + sc[3];
        const float base_loss = B_ / (float)((long long)nrows * NATM);
        const float wfa_ml    = W_ / fmaxf(C_, 1.0f);
        const bool  apply     = (base_loss < 0.0004f) && (C_ > 0.f);
        out[0] = apply ? (0.5f * base_loss + 0.5f * wfa_ml) : base_loss;
        out[1] = base_loss;
        out[2] = apply ? wfa_ml : 0.f;
    }
}

extern "C" void kernel_launch(void* const* d_in, const int* in_sizes, int n_in,
                              void* d_out, int out_size, void* d_ws, size_t ws_size,
                              hipStream_t stream)
{
    const float* stokes = (const float*)d_in[0];
    const float* pred   = (const float*)d_in[1];
    const float* targ   = (const float*)d_in[2];
    const float* wl     = (const float*)d_in[3];
    float* out = (float*)d_out;
    float* ws  = (float*)d_ws;

    const int nrows = in_sizes[1] / NATM;   // 65536

    int nblocks = MAIN_BLOCKS;
    // safety: each block needs 3 floats of workspace
    const size_t need = (size_t)nblocks * 3 * sizeof(float);
    if (ws_size < need) {
        nblocks = (int)(ws_size / (3 * sizeof(float)));
        if (nblocks < 1) nblocks = 1;
    }

    hipLaunchKernelGGL(wfa_main, dim3(nblocks), dim3(THREADS), 0, stream,
                       stokes, pred, targ, wl, ws, nrows, nblocks);
    hipLaunchKernelGGL(wfa_final, dim3(1), dim3(256), 0, stream,
                       ws, out, nblocks, nrows);
}

// Round 2
// 199.060 us; speedup vs baseline: 1.0039x; 1.0039x over previous
//
#include <hip/hip_runtime.h>
#include <math.h>

#define NWL   112
#define NCOLS 111          // END - START = 111 usable columns
#define NATM  84
#define THREADS 256
#define WAVES_PER_BLOCK 4
#define MAIN_BLOCKS 2048

__device__ __forceinline__ float half_reduce_sum(float v) {
    // butterfly within each 32-lane half of the wave (xor offs <=16 never
    // cross the 32-lane boundary on wave64)
    v += __shfl_xor(v, 1,  64);
    v += __shfl_xor(v, 2,  64);
    v += __shfl_xor(v, 4,  64);
    v += __shfl_xor(v, 8,  64);
    v += __shfl_xor(v, 16, 64);
    return v;
}

__device__ __forceinline__ float wave_reduce_sum(float v) {
#pragma unroll
    for (int off = 32; off >= 1; off >>= 1)
        v += __shfl_xor(v, off, 64);
    return v;
}

__global__ __launch_bounds__(THREADS) void wfa_main(
    const float* __restrict__ stokes,   // (B, 4, 112)
    const float* __restrict__ pred,     // (B, 84)
    const float* __restrict__ targ,     // (B, 84)
    const float* __restrict__ wl,       // (112)
    float* __restrict__ ws,             // [nblk] base | [nblk] wfa | [nblk] cnt
    int nrows, int nblocks)
{
    __shared__ float s_idw[NWL];                  // 1/grad(wl), s_idw[111]=0 (excluded col)
    __shared__ float s_red[WAVES_PER_BLOCK][3];

    const int tid  = threadIdx.x;
    const int lane = tid & 63;
    const int wid  = tid >> 6;
    const int sub  = lane & 31;       // position within half-wave
    const int g    = lane & 32;       // half base (0 or 32)

    // grad(wl) over the truncated 111-col array, per reference _np_gradient.
    // float32 cancellation makes dwl vary ~1% per j: must use actual wl input.
    if (tid < NWL) {
        const int j = tid;
        float d;
        if (j == 0)              d = wl[1] - wl[0];
        else if (j == NCOLS - 1) d = wl[NCOLS - 1] - wl[NCOLS - 2];
        else if (j < NCOLS - 1)  d = 0.5f * (wl[j + 1] - wl[j - 1]);
        else                     d = 1.0f;                 // j==111 (excluded)
        s_idw[j] = (j == NCOLS) ? 0.0f : 1.0f / d;
    }
    __syncthreads();

    // per-lane gradient scale, loaded ONCE (constant across rows)
    float4 idw4 = make_float4(0.f, 0.f, 0.f, 0.f);
    if (sub < 28) idw4 = *(const float4*)&s_idw[4 * sub];

    const float WFA_DEN = (float)(4.6686e-13 * 6301.5 * 6301.5 * 1.5);

    // one row per HALF-wave
    const int h  = (blockIdx.x * WAVES_PER_BLOCK + wid) * 2 + (lane >> 5);
    const int nh = nblocks * WAVES_PER_BLOCK * 2;

    float base_acc = 0.f;
    float wfa_acc  = 0.f;   // sub==0 lanes only
    float cnt_acc  = 0.f;

    for (int r = h; r < nrows; r += nh) {
        const float* rowbase = stokes + (size_t)r * (4 * NWL);

        float4 I4 = make_float4(0.f, 0.f, 0.f, 0.f);
        float4 V4 = make_float4(0.f, 0.f, 0.f, 0.f);
        if (sub < 28) {
            I4 = ((const float4*)rowbase)[sub];                 // ch 0
            V4 = ((const float4*)(rowbase + 3 * NWL))[sub];     // ch 3
        }

        float4 P4 = make_float4(0.f, 0.f, 0.f, 0.f);
        float bpart = 0.f;
        if (sub < 21) {
            P4 = ((const float4*)(pred + (size_t)r * NATM))[sub];
            const float4 T4 = ((const float4*)(targ + (size_t)r * NATM))[sub];
            bpart = fabsf(P4.x - T4.x) + fabsf(P4.y - T4.y)
                  + fabsf(P4.z - T4.z) + fabsf(P4.w - T4.w);
        }
        base_acc += bpart;

        // gradient neighbors from adjacent lanes (no LDS round-trip)
        const int lm1 = lane - (sub ? 1 : 0);
        const float im1 = __shfl(I4.w, lm1, 64);       // I[4*sub - 1]
        const float ip4 = __shfl(I4.x, lane + 1, 64);  // I[4*sub + 4] (lane g+28 holds 0)

        // np.gradient numerators; j = 4*sub + c
        const float n0 = (sub == 0)  ? (I4.y - I4.x) : 0.5f * (I4.y - im1);
        const float n1 = 0.5f * (I4.z - I4.x);
        const float n2 = (sub == 27) ? (I4.z - I4.y) : 0.5f * (I4.w - I4.y);
        const float n3 = 0.5f * (ip4 - I4.z);          // j=111 killed by idw4.w=0

        const float d0 = n0 * idw4.x;
        const float d1 = n1 * idw4.y;
        const float d2 = n2 * idw4.z;
        const float d3 = n3 * idw4.w;
        const float v3 = (sub == 27) ? 0.f : V4.w;     // col 111 excluded from sums

        float sd  = d0 + d1 + d2 + d3;
        float sdd = fmaf(d0, d0, fmaf(d1, d1, fmaf(d2, d2, d3 * d3)));
        float sdv = fmaf(d0, V4.x, fmaf(d1, V4.y, fmaf(d2, V4.z, d3 * v3)));
        float sv  = V4.x + V4.y + V4.z + v3;

        sd  = half_reduce_sum(sd);
        sdd = half_reduce_sum(sdd);
        sdv = half_reduce_sum(sdv);
        sv  = half_reduce_sum(sv);

        // a[3],a[7],a[11] = P4.w of sub 0,1,2 in this half
        const float a7  = __shfl(P4.w, g | 1, 64);
        const float a11 = __shfl(P4.w, g | 2, 64);

        if (sub == 0) {
            const float n  = (float)NCOLS;
            const float p0 = (n * sdv - sd * sv) / (n * sdd - sd * sd);
            const float ab = fabsf(p0) / WFA_DEN;      // |wfa_blos|
            if (ab < 100.0f) {
                const float pb = (P4.w + a7 + a11) / 3.0f;
                wfa_acc += fabsf(log10f(fabsf(pb) + 1e-10f) - log10f(ab + 1e-10f));
                cnt_acc += 1.0f;
            }
        }
    }

    base_acc = wave_reduce_sum(base_acc);
    wfa_acc  = wave_reduce_sum(wfa_acc);   // nonzero only on lanes 0,32
    cnt_acc  = wave_reduce_sum(cnt_acc);
    if (lane == 0) {
        s_red[wid][0] = base_acc;
        s_red[wid][1] = wfa_acc;
        s_red[wid][2] = cnt_acc;
    }
    __syncthreads();
    if (tid == 0) {
        float b = 0.f, w = 0.f, c = 0.f;
#pragma unroll
        for (int k = 0; k < WAVES_PER_BLOCK; ++k) {
            b += s_red[k][0]; w += s_red[k][1]; c += s_red[k][2];
        }
        ws[blockIdx.x]               = b;
        ws[nblocks + blockIdx.x]     = w;
        ws[2 * nblocks + blockIdx.x] = c;
    }
}

__global__ __launch_bounds__(256) void wfa_final(
    const float* __restrict__ ws, float* __restrict__ out,
    int nblocks, int nrows)
{
    const int tid = threadIdx.x;
    float b = 0.f, w = 0.f, c = 0.f;
    for (int i = tid; i < nblocks; i += 256) {
        b += ws[i];
        w += ws[nblocks + i];
        c += ws[2 * nblocks + i];
    }
    b = wave_reduce_sum(b);
    w = wave_reduce_sum(w);
    c = wave_reduce_sum(c);

    __shared__ float sb[4], sw[4], sc[4];
    const int lane = tid & 63, wid = tid >> 6;
    if (lane == 0) { sb[wid] = b; sw[wid] = w; sc[wid] = c; }
    __syncthreads();
    if (tid == 0) {
        const float B_ = sb[0] + sb[1] + sb[2] + sb[3];
        const float W_ = sw[0] + sw[1] + sw[2] + sw[3];
        const float C_ = sc[0] + sc[1] + sc[2] + sc[3];
        const float base_loss = B_ / (float)((long long)nrows * NATM);
        const float wfa_ml    = W_ / fmaxf(C_, 1.0f);
        const bool  apply     = (base_loss < 0.0004f) && (C_ > 0.f);
        out[0] = apply ? (0.5f * base_loss + 0.5f * wfa_ml) : base_loss;
        out[1] = base_loss;
        out[2] = apply ? wfa_ml : 0.f;
    }
}

extern "C" void kernel_launch(void* const* d_in, const int* in_sizes, int n_in,
                              void* d_out, int out_size, void* d_ws, size_t ws_size,
                              hipStream_t stream)
{
    const float* stokes = (const float*)d_in[0];
    const float* pred   = (const float*)d_in[1];
    const float* targ   = (const float*)d_in[2];
    const float* wl     = (const float*)d_in[3];
    float* out = (float*)d_out;
    float* ws  = (float*)d_ws;

    const int nrows = in_sizes[1] / NATM;   // 65536

    int nblocks = MAIN_BLOCKS;
    const size_t need = (size_t)nblocks * 3 * sizeof(float);
    if (ws_size < need) {
        nblocks = (int)(ws_size / (3 * sizeof(float)));
        if (nblocks < 1) nblocks = 1;
    }

    hipLaunchKernelGGL(wfa_main, dim3(nblocks), dim3(THREADS), 0, stream,
                       stokes, pred, targ, wl, ws, nrows, nblocks);
    hipLaunchKernelGGL(wfa_final, dim3(1), dim3(256), 0, stream,
                       ws, out, nblocks, nrows);
}